// Round 17
// baseline (300.200 us; speedup 1.0000x reference)
//
#include <hip/hip_runtime.h>
#include <stdint.h>

typedef __bf16 bf16x8 __attribute__((ext_vector_type(8)));
typedef float f32x4 __attribute__((ext_vector_type(4)));

union FragU { uint4 q; bf16x8 v; };

__device__ __forceinline__ float bf2f(uint32_t h){
  union U{uint32_t u; float f;} x; x.u = h<<16; return x.f;
}
__device__ __forceinline__ uint32_t f2bf(float f){
  union U{float f; uint32_t u;} x; x.f=f;
  return (x.u + 0x7FFFu + ((x.u>>16)&1u)) >> 16;
}
__device__ __forceinline__ float lrelu(float x){ return fmaxf(x, 0.1f*x); }

// ------------------------- KNN v4 (R15 config) -------------------------
__global__ __launch_bounds__(256) void knn_kernel(const float* __restrict__ points, int* __restrict__ idx){
  __shared__ float sx[1024], sy[1024], sz[1024];
  __shared__ double srq[1024];
  __shared__ unsigned long long scand[4][64];
  const int n = blockIdx.y;
  const float* P = points + (size_t)n*1024*3;
  for(int q=threadIdx.x; q<1024; q+=256){
    float x=P[q*3+0], y=P[q*3+1], z=P[q*3+2];
    sx[q]=x; sy[q]=y; sz[q]=z;
    srq[q] = (double)x*(double)x + (double)y*(double)y + (double)z*(double)z;
  }
  __syncthreads();
  const int wv = threadIdx.x>>6;
  const int lane = threadIdx.x & 63;
  const int p = blockIdx.x*4 + wv;
  const double px=sx[p], py=sy[p], pz=sz[p];
  const double rp = srq[p];
  float key[16];
  const int prel = p - lane;
  #pragma unroll
  for(int j=0;j<16;j++){
    const int q = lane + j*64;
    double qx=sx[q], qy=sy[q], qz=sz[q];
    double dot = px*qx+py*qy+pz*qz;
    float k = fmaxf((float)((rp + srq[q]) - 2.0*dot), 0.0f);
    if(prel == j*64) k = __builtin_inff();
    key[j] = k;
  }
  float hk = key[0];
  #pragma unroll
  for(int j=1;j<16;j++) hk = fminf(hk, key[j]);
  {
    float hs = hk;
    #pragma unroll
    for(int k=2;k<=64;k<<=1){
      #pragma unroll
      for(int j=32;j>0;j>>=1){
        if(j < k){
          float o = __shfl_xor(hs, j);
          const bool keepMax = (((lane & j)!=0) ^ ((lane & k)!=0));
          hs = keepMax ? fmaxf(hs,o) : fminf(hs,o);
        }
      }
    }
    hk = hs;
  }
  const float Hk = __shfl(hk, 15);
  int cnt = 0;
  #pragma unroll
  for(int j=0;j<16;j++) cnt += (key[j] <= Hk) ? 1 : 0;
  int inc = cnt;
  #pragma unroll
  for(int d=1; d<64; d<<=1){
    int t = __shfl_up(inc, d);
    if(lane >= d) inc += t;
  }
  const int m = __shfl(inc, 63);
  const int base = inc - cnt;
  int* op = idx + ((size_t)n*1024 + p)*16;
  if(m <= 64){
    unsigned long long* sc = scand[wv];
    int slot = base;
    #pragma unroll
    for(int j=0;j<16;j++){
      if(key[j] <= Hk){
        sc[slot] = ((unsigned long long)__float_as_uint(key[j]) << 10) | (unsigned)(lane + j*64);
        slot++;
      }
    }
    unsigned long long v = (lane < m) ? sc[lane] : ~0ULL;
    #pragma unroll
    for(int k=2;k<=64;k<<=1){
      #pragma unroll
      for(int j=32;j>0;j>>=1){
        if(j < k){
          unsigned long long o = __shfl_xor(v, j);
          const bool keepMax = (((lane & j)!=0) ^ ((lane & k)!=0));
          v = keepMax ? (v > o ? v : o) : (v < o ? v : o);
        }
      }
    }
    if(lane < 16) op[lane] = (int)(v & 1023u);
  } else {
    unsigned long long e[16];
    #pragma unroll
    for(int j=0;j<16;j++)
      e[j] = ((unsigned long long)__float_as_uint(key[j]) << 10) | (unsigned)(lane + j*64);
    for(int it=0; it<16; ++it){
      unsigned long long bd = e[0];
      #pragma unroll
      for(int j=1;j<16;j++) bd = (e[j] < bd) ? e[j] : bd;
      unsigned long long pk = bd;
      #pragma unroll
      for(int s=1;s<64;s<<=1){
        unsigned long long o = __shfl_xor(pk, s);
        pk = (o < pk) ? o : pk;
      }
      #pragma unroll
      for(int j=0;j<16;j++) e[j] = (e[j]==pk) ? ~0ULL : e[j];
      if(lane==0) op[it] = (int)(pk & 1023u);
    }
  }
}

// ------------------------- W prep: bf16 fragment-major layouts -------------------------
__global__ void wprep_kernel(const float* __restrict__ W0, const float* __restrict__ Wsc,
                             const float* __restrict__ W1, const float* __restrict__ W2,
                             uint16_t* __restrict__ Wpp, uint16_t* __restrict__ W1p,
                             uint16_t* __restrict__ W2p){
  const int stride = gridDim.x*blockDim.x;
  const int t0 = blockIdx.x*blockDim.x + threadIdx.x;
  for(int o=t0; o<32768; o+=stride){
    int j=o&7, l=(o>>3)&63, kc=(o>>9)&1, ct=(o>>10)&3, w=o>>12;
    int k = kc*32 + (l>>4)*8 + j;
    int c = w*64 + ct*16 + (l&15);
    float val;
    if(c<128)      val = W0[k*128+c] - W0[(k+64)*128+c];
    else if(c<256) val = W0[(k+64)*128 + (c-128)];
    else           val = Wsc[k*256 + (c-256)];
    Wpp[o] = (uint16_t)f2bf(val);
  }
  for(int o=t0; o<16384; o+=stride){
    int j=o&7, l=(o>>3)&63, kc=(o>>9)&3, ct=(o>>11)&1, w=o>>12;
    int k = kc*32 + (l>>4)*8 + j, c = w*32 + ct*16 + (l&15);
    W1p[o] = (uint16_t)f2bf(W1[k*128+c]);
  }
  for(int o=t0; o<32768; o+=stride){
    int j=o&7, l=(o>>3)&63, kc=(o>>9)&3, ct=(o>>11)&3, w=o>>13;
    int k = kc*32 + (l>>4)*8 + j, c = w*64 + ct*16 + (l&15);
    W2p[o] = (uint16_t)f2bf(W2[k*256+c]);
  }
}

// ------------------------- projections (MFMA) -------------------------
__global__ __launch_bounds__(512) void proj_kernel(const float* __restrict__ feat,
    const uint16_t* __restrict__ Wpp,
    float* __restrict__ F1, float* __restrict__ F2, float* __restrict__ Fsc,
    float* __restrict__ screps){
  __shared__ alignas(16) uint16_t sA[64*64];
  const int b = blockIdx.x;
  const int tid = threadIdx.x;
  {
    const int row = tid>>3, cc = tid&7;
    const float* src = feat + ((size_t)b*64+row)*64 + cc*8;
    const float4 f0 = *(const float4*)(src);
    const float4 f1 = *(const float4*)(src+4);
    uint32_t pk[4] = { f2bf(f0.x)|(f2bf(f0.y)<<16), f2bf(f0.z)|(f2bf(f0.w)<<16),
                       f2bf(f1.x)|(f2bf(f1.y)<<16), f2bf(f1.z)|(f2bf(f1.w)<<16) };
    int bo = row*128 + cc*16; bo ^= (row&7)<<4;
    *(uint4*)((char*)sA + bo) = make_uint4(pk[0],pk[1],pk[2],pk[3]);
  }
  __syncthreads();
  const int w = tid>>6, l = tid&63;
  FragU bfr[4][2];
  #pragma unroll
  for(int ct=0;ct<4;ct++)
    #pragma unroll
    for(int kc=0;kc<2;kc++)
      bfr[ct][kc].q = *(const uint4*)(Wpp + ((size_t)((w*4+ct)*2+kc))*512 + l*8);
  f32x4 acc[4][4] = {};
  #pragma unroll
  for(int rt=0;rt<4;rt++){
    FragU a[2];
    #pragma unroll
    for(int kc=0;kc<2;kc++){
      const int row = rt*16 + (l&15);
      int bo = row*128 + kc*64 + (l>>4)*16; bo ^= (row&7)<<4;
      a[kc].q = *(const uint4*)((const char*)sA + bo);
    }
    #pragma unroll
    for(int ct=0;ct<4;ct++)
      #pragma unroll
      for(int kc=0;kc<2;kc++)
        acc[rt][ct] = __builtin_amdgcn_mfma_f32_16x16x32_bf16(a[kc].v, bfr[ct][kc].v, acc[rt][ct], 0,0,0);
  }
  #pragma unroll
  for(int rt=0;rt<4;rt++){
    #pragma unroll
    for(int ct=0;ct<4;ct++){
      const int c = w*64 + ct*16 + (l&15);
      const int rowg = b*64 + rt*16 + (l>>4)*4;
      #pragma unroll
      for(int reg=0;reg<4;reg++){
        float v = acc[rt][ct][reg];
        if(c < 128)      F1[(size_t)(rowg+reg)*128 + c] = v;
        else if(c < 256) F2[(size_t)(rowg+reg)*128 + (c-128)] = v;
        else             Fsc[(size_t)(rowg+reg)*256 + (c-256)] = v;
      }
    }
  }
  if(w>=4){
    #pragma unroll
    for(int ct=0;ct<4;ct++){
      float s=0.f, sq=0.f;
      #pragma unroll
      for(int rt=0;rt<4;rt++)
        #pragma unroll
        for(int reg=0;reg<4;reg++){ float v=acc[rt][ct][reg]; s+=v; sq+=v*v; }
      s += __shfl_xor(s,16); sq += __shfl_xor(sq,16);
      s += __shfl_xor(s,32); sq += __shfl_xor(sq,32);
      if(l<16){
        const int c = (w-4)*64 + ct*16 + l;
        atomicAdd(&screps[((b&31)*2+0)*256 + c], s);
        atomicAdd(&screps[((b&31)*2+1)*256 + c], sq);
      }
    }
  }
}

// ------------------------- y0 stats -------------------------
__global__ __launch_bounds__(256) void y0stats_kernel(const float* __restrict__ F1,
    const float* __restrict__ F2, const int* __restrict__ idx, float* __restrict__ reps){
  __shared__ int sIdx[256];
  const int tid = threadIdx.x;
  const int r0 = blockIdx.x*256;
  sIdx[tid] = idx[r0 + tid];
  __syncthreads();
  const int cg = tid & 31;
  const int rs = tid >> 5;
  const int nbase = (r0 >> 14) << 10;
  f32x4 s = {0,0,0,0}, sq = {0,0,0,0};
  for(int rr=0; rr<32; rr+=4){
    #pragma unroll
    for(int u=0;u<4;u++){
      const int r = rs*32 + rr + u;
      const int np = (r0 + r) >> 4;
      const int g = sIdx[r];
      const float4 a = *(const float4*)(F1 + (size_t)np*128 + cg*4);
      const float4 c = *(const float4*)(F2 + (size_t)(nbase + g)*128 + cg*4);
      float v0=a.x+c.x, v1=a.y+c.y, v2=a.z+c.z, v3=a.w+c.w;
      s[0]+=v0; s[1]+=v1; s[2]+=v2; s[3]+=v3;
      sq[0]+=v0*v0; sq[1]+=v1*v1; sq[2]+=v2*v2; sq[3]+=v3*v3;
    }
  }
  #pragma unroll
  for(int e=0;e<4;e++){
    s[e]  += __shfl_xor(s[e], 32);
    sq[e] += __shfl_xor(sq[e], 32);
  }
  if((tid&63) < 32){
    const int rep = blockIdx.x & 31;
    #pragma unroll
    for(int e=0;e<4;e++){
      atomicAdd(&reps[(rep*2+0)*128 + cg*4+e], s[e]);
      atomicAdd(&reps[(rep*2+1)*128 + cg*4+e], sq[e]);
    }
  }
}

// ------------------------- finalize BN -------------------------
__global__ void finalize_kernel(const float* __restrict__ reps, const float* __restrict__ gamma,
    const float* __restrict__ beta, float* __restrict__ s, float* __restrict__ t,
    int C, float inv_cnt){
  int c = threadIdx.x;
  if(c>=C) return;
  float sum=0.f, sq=0.f;
  for(int r2=0;r2<32;r2++){ sum += reps[(r2*2+0)*C + c]; sq += reps[(r2*2+1)*C + c]; }
  float m = sum*inv_cnt;
  float var = sq*inv_cnt - m*m;
  float sc = gamma[c]*rsqrtf(var + 1e-3f);
  s[c]=sc; t[c]=beta[c] - m*sc;
}

// ------------------------- layer1 v3: tile-loop, 8 waves, double-buffered LDS -------------------------
// grid 512 x 512 thr; block = 16 tiles of 64 rows. Wave w owns cols w*16..w*16+15.
// Per iter: issue next tile's 8 gather float4s -> MFMA current tile -> y1 write + reg stats
// -> BN+pack regs into other buffer -> barrier. y1 element mapping identical to before:
// CI = (rt*8+w)*4+reg (== old ((rt*4+wv)*2+ct)*4+reg with w=wv*2+ct), so layer2s/f unchanged.
__global__ __launch_bounds__(512) void layer1_kernel(
    const float* __restrict__ F1, const float* __restrict__ F2, const int* __restrict__ idx,
    const uint16_t* __restrict__ W1p, const float* __restrict__ s0, const float* __restrict__ t0,
    uint16_t* __restrict__ y1, float* __restrict__ reps1){
  __shared__ alignas(16) uint16_t sA[2][8192];
  __shared__ int sIdx[1024];
  const int bb = blockIdx.x;
  const int tid = threadIdx.x;
  const int w = tid>>6, l = tid&63;
  sIdx[tid]      = idx[bb*1024 + tid];
  sIdx[512+tid]  = idx[bb*1024 + 512 + tid];
  const int row = tid>>3, q = tid&7;           // staging: row 0..63, 16-ch group q
  const int nbase = (bb>>4)<<10;               // n constant per block (16 tiles span < 256)
  // hoisted BN consts for channels q*16..q*16+15
  float scv[16], ttv[16];
  #pragma unroll
  for(int e4=0;e4<4;e4++){
    const float4 sv = *(const float4*)(s0 + q*16 + e4*4);
    const float4 tv = *(const float4*)(t0 + q*16 + e4*4);
    scv[e4*4+0]=sv.x; scv[e4*4+1]=sv.y; scv[e4*4+2]=sv.z; scv[e4*4+3]=sv.w;
    ttv[e4*4+0]=tv.x; ttv[e4*4+1]=tv.y; ttv[e4*4+2]=tv.z; ttv[e4*4+3]=tv.w;
  }
  // W fragments: wave w = col-tile w
  FragU bfr[4];
  #pragma unroll
  for(int kc=0;kc<4;kc++)
    bfr[kc].q = *(const uint4*)(W1p + ((size_t)(w*4+kc))*512 + l*8);
  __syncthreads();   // sIdx ready
  // prologue: stage tile 0 directly
  {
    const int bt = bb*16;
    const int np = bt*4 + (row>>4);
    const int g  = sIdx[row];
    const float* pf1 = F1 + (size_t)np*128 + q*16;
    const float* pf2 = F2 + (size_t)(nbase+g)*128 + q*16;
    float4 a0=*(const float4*)(pf1), a1=*(const float4*)(pf1+4),
           a2=*(const float4*)(pf1+8), a3=*(const float4*)(pf1+12);
    float4 c0=*(const float4*)(pf2), c1=*(const float4*)(pf2+4),
           c2=*(const float4*)(pf2+8), c3=*(const float4*)(pf2+12);
    float v[16]={a0.x+c0.x,a0.y+c0.y,a0.z+c0.z,a0.w+c0.w, a1.x+c1.x,a1.y+c1.y,a1.z+c1.z,a1.w+c1.w,
                 a2.x+c2.x,a2.y+c2.y,a2.z+c2.z,a2.w+c2.w, a3.x+c3.x,a3.y+c3.y,a3.z+c3.z,a3.w+c3.w};
    uint32_t pk[8];
    #pragma unroll
    for(int e=0;e<8;e++){
      float x0 = lrelu(scv[e*2]*v[e*2] + ttv[e*2]);
      float x1 = lrelu(scv[e*2+1]*v[e*2+1] + ttv[e*2+1]);
      pk[e] = f2bf(x0) | (f2bf(x1)<<16);
    }
    const int sw = (row&7)<<4;
    const int bo = row*256 + q*32;
    *(uint4*)((char*)sA[0] + (bo ^ sw))      = make_uint4(pk[0],pk[1],pk[2],pk[3]);
    *(uint4*)((char*)sA[0] + ((bo+16) ^ sw)) = make_uint4(pk[4],pk[5],pk[6],pk[7]);
  }
  __syncthreads();
  float ssA = 0.f, sqA = 0.f;      // per-thread stats for col w*16+(l&15)
  for(int t=0; t<16; ++t){
    const int bt = bb*16 + t;
    const int p = t&1;
    // prefetch next tile's gather into regs
    float4 a0,a1,a2,a3,c0,c1,c2,c3;
    if(t<15){
      const int np = (bt+1)*4 + (row>>4);
      const int g  = sIdx[(t+1)*64 + row];
      const float* pf1 = F1 + (size_t)np*128 + q*16;
      const float* pf2 = F2 + (size_t)(nbase+g)*128 + q*16;
      a0=*(const float4*)(pf1); a1=*(const float4*)(pf1+4);
      a2=*(const float4*)(pf1+8); a3=*(const float4*)(pf1+12);
      c0=*(const float4*)(pf2); c1=*(const float4*)(pf2+4);
      c2=*(const float4*)(pf2+8); c3=*(const float4*)(pf2+12);
    }
    // MFMA current tile
    f32x4 acc[4] = {};
    #pragma unroll
    for(int rt=0;rt<4;rt++){
      FragU a[4];
      #pragma unroll
      for(int kc=0;kc<4;kc++){
        const int rw = rt*16 + (l&15);
        int bo = rw*256 + kc*64 + (l>>4)*16; bo ^= (rw&7)<<4;
        a[kc].q = *(const uint4*)((const char*)sA[p] + bo);
      }
      #pragma unroll
      for(int kc=0;kc<4;kc++)
        acc[rt] = __builtin_amdgcn_mfma_f32_16x16x32_bf16(a[kc].v, bfr[kc].v, acc[rt], 0,0,0);
    }
    // epilogue: y1 write (fragment-tile layout) + stats
    #pragma unroll
    for(int rt=0;rt<4;rt++)
      #pragma unroll
      for(int reg=0;reg<4;reg++){
        float v = acc[rt][reg];
        ssA += v; sqA += v*v;
        y1[(size_t)bt*8192 + (size_t)(((rt*8+w)*4+reg))*64 + l] = (uint16_t)f2bf(v);
      }
    // BN+pack prefetched regs into the other buffer
    if(t<15){
      float v[16]={a0.x+c0.x,a0.y+c0.y,a0.z+c0.z,a0.w+c0.w, a1.x+c1.x,a1.y+c1.y,a1.z+c1.z,a1.w+c1.w,
                   a2.x+c2.x,a2.y+c2.y,a2.z+c2.z,a2.w+c2.w, a3.x+c3.x,a3.y+c3.y,a3.z+c3.z,a3.w+c3.w};
      uint32_t pk[8];
      #pragma unroll
      for(int e=0;e<8;e++){
        float x0 = lrelu(scv[e*2]*v[e*2] + ttv[e*2]);
        float x1 = lrelu(scv[e*2+1]*v[e*2+1] + ttv[e*2+1]);
        pk[e] = f2bf(x0) | (f2bf(x1)<<16);
      }
      const int sw = (row&7)<<4;
      const int bo = row*256 + q*32;
      *(uint4*)((char*)sA[p^1] + (bo ^ sw))      = make_uint4(pk[0],pk[1],pk[2],pk[3]);
      *(uint4*)((char*)sA[p^1] + ((bo+16) ^ sw)) = make_uint4(pk[4],pk[5],pk[6],pk[7]);
    }
    __syncthreads();
  }
  // stats reduction: lanes {l, l+16, l+32, l+48} share col w*16+(l&15)
  ssA += __shfl_xor(ssA,16); sqA += __shfl_xor(sqA,16);
  ssA += __shfl_xor(ssA,32); sqA += __shfl_xor(sqA,32);
  if(l < 16){
    const int c = w*16 + l;
    const int rep = bb & 31;
    atomicAdd(&reps1[(rep*2+0)*128 + c], ssA);
    atomicAdd(&reps1[(rep*2+1)*128 + c], sqA);
  }
}

// ------------------------- layer2 pass A: stats + export transformed tiles -------------------------
__global__ __launch_bounds__(512, 4) void layer2s_kernel(
    uint16_t* __restrict__ y1, const uint16_t* __restrict__ W2p,
    const float* __restrict__ s1, const float* __restrict__ t1,
    float* __restrict__ reps2){
  __shared__ alignas(16) uint16_t sA[2][8192];
  __shared__ float sBN[256];
  const int tid = threadIdx.x;
  const int w = tid>>6, l = tid&63;
  if(tid<128){ sBN[tid]=s1[tid]; sBN[128+tid]=t1[tid]; }
  FragU bfr[2][4];
  #pragma unroll
  for(int ct=0;ct<2;ct++)
    #pragma unroll
    for(int kc=0;kc<4;kc++)
      bfr[ct][kc].q = *(const uint4*)(W2p + ((size_t)((w*2+ct)*4+kc))*512 + l*8);
  int uc0[2], ubo[2];
  #pragma unroll
  for(int k=0;k<2;k++){
    const int u = tid + k*512;
    const int l8 = u&7, CI = u>>3;
    const int reg = CI&3, ct = (CI>>2)&1, w8 = (CI>>3)&3, rt = CI>>5;
    const int row = rt*16 + (l8>>1)*4 + reg;
    const int c0 = w8*32 + ct*16 + (l8&1)*8;
    uc0[k] = c0;
    ubo[k] = (row*256 + c0*2) ^ ((row&7)<<4);
  }
  const int bt0 = blockIdx.x*16;
  uint4 va[2];
  #pragma unroll
  for(int k=0;k<2;k++)
    va[k] = *(const uint4*)(y1 + (size_t)bt0*8192 + (size_t)(tid+k*512)*8);
  __syncthreads();   // sBN ready
  #pragma unroll
  for(int k=0;k<2;k++){
    const float4 sa = *(const float4*)(&sBN[uc0[k]]);
    const float4 sb = *(const float4*)(&sBN[uc0[k]+4]);
    const float4 ta = *(const float4*)(&sBN[128+uc0[k]]);
    const float4 tb = *(const float4*)(&sBN[128+uc0[k]+4]);
    const float scv[8]={sa.x,sa.y,sa.z,sa.w, sb.x,sb.y,sb.z,sb.w};
    const float ttv[8]={ta.x,ta.y,ta.z,ta.w, tb.x,tb.y,tb.z,tb.w};
    const uint32_t e[4] = {va[k].x, va[k].y, va[k].z, va[k].w};
    uint32_t pk[4];
    #pragma unroll
    for(int j=0;j<4;j++){
      float x0 = lrelu(scv[j*2]*bf2f(e[j]&0xffffu) + ttv[j*2]);
      float x1 = lrelu(scv[j*2+1]*bf2f(e[j]>>16) + ttv[j*2+1]);
      pk[j] = f2bf(x0) | (f2bf(x1)<<16);
    }
    *(uint4*)((char*)sA[0] + ubo[k]) = make_uint4(pk[0],pk[1],pk[2],pk[3]);
  }
  __syncthreads();
  float ssA[2]={0,0}, sqA[2]={0,0};
  for(int t=0; t<16; ++t){
    const int bt = bt0 + t;
    const int p = t&1;
    if(t<15){
      #pragma unroll
      for(int k=0;k<2;k++)
        va[k] = *(const uint4*)(y1 + (size_t)(bt+1)*8192 + (size_t)(tid+k*512)*8);
    }
    f32x4 acc[4][2] = {};
    #pragma unroll
    for(int rt=0;rt<4;rt++){
      FragU a[4];
      #pragma unroll
      for(int kc=0;kc<4;kc++){
        const int rw = rt*16 + (l&15);
        int bo = rw*256 + kc*64 + (l>>4)*16; bo ^= (rw&7)<<4;
        a[kc].q = *(const uint4*)((const char*)sA[p] + bo);
      }
      if(w==0){   // export this tile's frags (fragment-major, coalesced 1KB runs)
        #pragma unroll
        for(int kc=0;kc<4;kc++)
          *(uint4*)(y1 + (size_t)bt*8192 + (size_t)((rt*4+kc)*64 + l)*8) = a[kc].q;
      }
      #pragma unroll
      for(int ct=0;ct<2;ct++)
        #pragma unroll
        for(int kc=0;kc<4;kc++)
          acc[rt][ct] = __builtin_amdgcn_mfma_f32_16x16x32_bf16(a[kc].v, bfr[ct][kc].v, acc[rt][ct], 0,0,0);
    }
    #pragma unroll
    for(int ct=0;ct<2;ct++)
      #pragma unroll
      for(int rt=0;rt<4;rt++)
        #pragma unroll
        for(int reg=0;reg<4;reg++){
          float v = acc[rt][ct][reg];
          ssA[ct]+=v; sqA[ct]+=v*v;
        }
    if(t<15){
      #pragma unroll
      for(int k=0;k<2;k++){
        const float4 sa = *(const float4*)(&sBN[uc0[k]]);
        const float4 sb = *(const float4*)(&sBN[uc0[k]+4]);
        const float4 ta = *(const float4*)(&sBN[128+uc0[k]]);
        const float4 tb = *(const float4*)(&sBN[128+uc0[k]+4]);
        const float scv[8]={sa.x,sa.y,sa.z,sa.w, sb.x,sb.y,sb.z,sb.w};
        const float ttv[8]={ta.x,ta.y,ta.z,ta.w, tb.x,tb.y,tb.z,tb.w};
        const uint32_t e[4] = {va[k].x, va[k].y, va[k].z, va[k].w};
        uint32_t pk[4];
        #pragma unroll
        for(int j=0;j<4;j++){
          float x0 = lrelu(scv[j*2]*bf2f(e[j]&0xffffu) + ttv[j*2]);
          float x1 = lrelu(scv[j*2+1]*bf2f(e[j]>>16) + ttv[j*2+1]);
          pk[j] = f2bf(x0) | (f2bf(x1)<<16);
        }
        *(uint4*)((char*)sA[p^1] + ubo[k]) = make_uint4(pk[0],pk[1],pk[2],pk[3]);
      }
    }
    __syncthreads();
  }
  #pragma unroll
  for(int ct=0;ct<2;ct++){
    float a=ssA[ct], b2=sqA[ct];
    a += __shfl_xor(a,16); b2 += __shfl_xor(b2,16);
    a += __shfl_xor(a,32); b2 += __shfl_xor(b2,32);
    if((l>>4)==0){
      const int c = w*32 + ct*16 + l;
      const int rep = blockIdx.x & 31;
      atomicAdd(&reps2[(rep*2+0)*256 + c], a);
      atomicAdd(&reps2[(rep*2+1)*256 + c], b2);
    }
  }
}

// ------------------------- layer2 pass B: gload_lds consumer, 2 tiles/phase -------------------------
__global__ __launch_bounds__(512, 4) void layer2f_kernel(
    const uint16_t* __restrict__ y1b, const uint16_t* __restrict__ W2p,
    const float* __restrict__ s2, const float* __restrict__ t2,
    const float* __restrict__ Fsc, const float* __restrict__ ssc, const float* __restrict__ tsc,
    float* __restrict__ out){
  __shared__ alignas(16) uint16_t sA[2][16384];
  const int tid = threadIdx.x;
  const int w = tid>>6, l = tid&63;
  FragU bfr[2][4];
  #pragma unroll
  for(int ct=0;ct<2;ct++)
    #pragma unroll
    for(int kc=0;kc<4;kc++)
      bfr[ct][kc].q = *(const uint4*)(W2p + ((size_t)((w*2+ct)*4+kc))*512 + l*8);
  float sc2v[2], tt2v[2], sscv[2], tscv[2];
  #pragma unroll
  for(int ct=0;ct<2;ct++){
    const int c = w*32 + ct*16 + (l&15);
    sc2v[ct]=s2[c]; tt2v[ct]=t2[c]; sscv[ct]=ssc[c]; tscv[ct]=tsc[c];
  }
  const int bt0 = blockIdx.x*16;
  {
    const uint16_t* gp = y1b + (size_t)bt0*8192 + w*512 + l*8;
    __builtin_amdgcn_global_load_lds((const uint32_t*)gp,         (uint32_t*)&sA[0][w*512 + l*8],         16, 0, 0);
    __builtin_amdgcn_global_load_lds((const uint32_t*)(gp+4096),  (uint32_t*)&sA[0][4096 + w*512 + l*8],  16, 0, 0);
    __builtin_amdgcn_global_load_lds((const uint32_t*)(gp+8192),  (uint32_t*)&sA[0][8192 + w*512 + l*8],  16, 0, 0);
    __builtin_amdgcn_global_load_lds((const uint32_t*)(gp+12288), (uint32_t*)&sA[0][12288 + w*512 + l*8], 16, 0, 0);
  }
  __syncthreads();
  for(int ph=0; ph<8; ++ph){
    const int p = ph&1;
    if(ph<7){
      const uint16_t* gp = y1b + (size_t)(bt0 + (ph+1)*2)*8192 + w*512 + l*8;
      __builtin_amdgcn_global_load_lds((const uint32_t*)gp,         (uint32_t*)&sA[p^1][w*512 + l*8],         16, 0, 0);
      __builtin_amdgcn_global_load_lds((const uint32_t*)(gp+4096),  (uint32_t*)&sA[p^1][4096 + w*512 + l*8],  16, 0, 0);
      __builtin_amdgcn_global_load_lds((const uint32_t*)(gp+8192),  (uint32_t*)&sA[p^1][8192 + w*512 + l*8],  16, 0, 0);
      __builtin_amdgcn_global_load_lds((const uint32_t*)(gp+12288), (uint32_t*)&sA[p^1][12288 + w*512 + l*8], 16, 0, 0);
    }
    #pragma unroll
    for(int tt=0; tt<2; ++tt){
      const int bt = bt0 + ph*2 + tt;
      f32x4 acc[4][2] = {};
      #pragma unroll
      for(int rt=0;rt<4;rt++){
        FragU a[4];
        #pragma unroll
        for(int kc=0;kc<4;kc++)
          a[kc].q = *(const uint4*)((const char*)sA[p] + (size_t)tt*16384 + (size_t)((rt*4+kc)*64 + l)*16);
        #pragma unroll
        for(int ct=0;ct<2;ct++)
          #pragma unroll
          for(int kc=0;kc<4;kc++)
            acc[rt][ct] = __builtin_amdgcn_mfma_f32_16x16x32_bf16(a[kc].v, bfr[ct][kc].v, acc[rt][ct], 0,0,0);
      }
      #pragma unroll
      for(int rt=0;rt<4;rt++){
        const int np = bt*4 + rt;
        #pragma unroll
        for(int ct=0;ct<2;ct++){
          const int c = w*32 + ct*16 + (l&15);
          float s=0.f;
          #pragma unroll
          for(int reg=0;reg<4;reg++) s += lrelu(sc2v[ct]*acc[rt][ct][reg] + tt2v[ct]);
          s += __shfl_xor(s,16);
          s += __shfl_xor(s,32);
          if((l>>4)==0){
            float fts = s*(1.0f/16.0f);
            float sc = sscv[ct]*Fsc[(size_t)np*256+c] + tscv[ct];
            out[(size_t)np*256+c] = lrelu(sc + fts);
          }
        }
      }
    }
    __syncthreads();   // drains gload_lds (vmcnt) + frag reads before buffer swap
  }
}

extern "C" void kernel_launch(void* const* d_in, const int* in_sizes, int n_in,
                              void* d_out, int out_size, void* d_ws, size_t ws_size,
                              hipStream_t stream) {
  const float* points   = (const float*)d_in[0];
  const float* features = (const float*)d_in[1];
  const float* W0  = (const float*)d_in[2];
  const float* g0  = (const float*)d_in[3];
  const float* b0  = (const float*)d_in[4];
  const float* W1  = (const float*)d_in[5];
  const float* g1  = (const float*)d_in[6];
  const float* b1  = (const float*)d_in[7];
  const float* W2  = (const float*)d_in[8];
  const float* g2  = (const float*)d_in[9];
  const float* b2  = (const float*)d_in[10];
  const float* Wsc = (const float*)d_in[11];
  const float* gsc = (const float*)d_in[12];
  const float* bsc = (const float*)d_in[13];
  float* out = (float*)d_out;

  float* ws = (float*)d_ws;
  size_t off = 0;
  float* screps = ws + off; off += 16384;    // [32][2][256]
  float* reps0  = ws + off; off += 8192;     // [32][2][128]
  float* reps1  = ws + off; off += 8192;
  float* reps2  = ws + off; off += 16384;
  float* ssc = ws + off; off += 256;
  float* tsc = ws + off; off += 256;
  float* s0  = ws + off; off += 128;
  float* t0  = ws + off; off += 128;
  float* s1v = ws + off; off += 128;
  float* t1v = ws + off; off += 128;
  float* s2v = ws + off; off += 256;
  float* t2v = ws + off; off += 256;
  int*   idxb = (int*)(ws + off); off += 524288;                 // [N*P*K]
  float* F1  = ws + off; off += (size_t)32768*128;
  float* F2  = ws + off; off += (size_t)32768*128;
  float* Fsc = ws + off; off += (size_t)32768*256;
  uint16_t* W1p = (uint16_t*)(ws + off); off += 8192;            // 16384 bf16
  uint16_t* W2p = (uint16_t*)(ws + off); off += 16384;           // 32768 bf16
  uint16_t* Wpp = (uint16_t*)(ws + off); off += 16384;           // 32768 bf16 combined proj W
  uint16_t* y1  = (uint16_t*)(ws + off); off += (size_t)33554432; // 524288*128 bf16; becomes y1b after layer2s

  // zero the stats replica region
  hipMemsetAsync(d_ws, 0, 49152*sizeof(float), stream);

  knn_kernel<<<dim3(256,32), 256, 0, stream>>>(points, idxb);
  wprep_kernel<<<128, 256, 0, stream>>>(W0, Wsc, W1, W2, Wpp, W1p, W2p);
  proj_kernel<<<512, 512, 0, stream>>>(features, Wpp, F1, F2, Fsc, screps);
  finalize_kernel<<<1, 256, 0, stream>>>(screps, gsc, bsc, ssc, tsc, 256, 1.0f/32768.0f);
  y0stats_kernel<<<2048, 256, 0, stream>>>(F1, F2, idxb, reps0);
  finalize_kernel<<<1, 128, 0, stream>>>(reps0, g0, b0, s0, t0, 128, 1.0f/524288.0f);
  layer1_kernel<<<512, 512, 0, stream>>>(F1, F2, idxb, W1p, s0, t0, y1, reps1);
  finalize_kernel<<<1, 128, 0, stream>>>(reps1, g1, b1, s1v, t1v, 128, 1.0f/524288.0f);
  layer2s_kernel<<<512, 512, 0, stream>>>(y1, W2p, s1v, t1v, reps2);
  finalize_kernel<<<1, 256, 0, stream>>>(reps2, g2, b2, s2v, t2v, 256, 1.0f/524288.0f);
  layer2f_kernel<<<512, 512, 0, stream>>>(y1, W2p, s2v, t2v, Fsc, ssc, tsc, out);
}

// Round 18
// 288.061 us; speedup vs baseline: 1.0421x; 1.0421x over previous
//
#include <hip/hip_runtime.h>
#include <stdint.h>

typedef __bf16 bf16x8 __attribute__((ext_vector_type(8)));
typedef float f32x4 __attribute__((ext_vector_type(4)));

union FragU { uint4 q; bf16x8 v; };

__device__ __forceinline__ float bf2f(uint32_t h){
  union U{uint32_t u; float f;} x; x.u = h<<16; return x.f;
}
__device__ __forceinline__ uint32_t f2bf(float f){
  union U{float f; uint32_t u;} x; x.f=f;
  return (x.u + 0x7FFFu + ((x.u>>16)&1u)) >> 16;
}
__device__ __forceinline__ float lrelu(float x){ return fmaxf(x, 0.1f*x); }

// ------------------------- KNN v4 -------------------------
__global__ __launch_bounds__(256) void knn_kernel(const float* __restrict__ points, int* __restrict__ idx){
  __shared__ float sx[1024], sy[1024], sz[1024];
  __shared__ double srq[1024];
  __shared__ unsigned long long scand[4][64];
  const int n = blockIdx.y;
  const float* P = points + (size_t)n*1024*3;
  for(int q=threadIdx.x; q<1024; q+=256){
    float x=P[q*3+0], y=P[q*3+1], z=P[q*3+2];
    sx[q]=x; sy[q]=y; sz[q]=z;
    srq[q] = (double)x*(double)x + (double)y*(double)y + (double)z*(double)z;
  }
  __syncthreads();
  const int wv = threadIdx.x>>6;
  const int lane = threadIdx.x & 63;
  const int p = blockIdx.x*4 + wv;
  const double px=sx[p], py=sy[p], pz=sz[p];
  const double rp = srq[p];
  float key[16];
  const int prel = p - lane;
  #pragma unroll
  for(int j=0;j<16;j++){
    const int q = lane + j*64;
    double qx=sx[q], qy=sy[q], qz=sz[q];
    double dot = px*qx+py*qy+pz*qz;
    float k = fmaxf((float)((rp + srq[q]) - 2.0*dot), 0.0f);
    if(prel == j*64) k = __builtin_inff();
    key[j] = k;
  }
  float hk = key[0];
  #pragma unroll
  for(int j=1;j<16;j++) hk = fminf(hk, key[j]);
  {
    float hs = hk;
    #pragma unroll
    for(int k=2;k<=64;k<<=1){
      #pragma unroll
      for(int j=32;j>0;j>>=1){
        if(j < k){
          float o = __shfl_xor(hs, j);
          const bool keepMax = (((lane & j)!=0) ^ ((lane & k)!=0));
          hs = keepMax ? fmaxf(hs,o) : fminf(hs,o);
        }
      }
    }
    hk = hs;
  }
  const float Hk = __shfl(hk, 15);
  int cnt = 0;
  #pragma unroll
  for(int j=0;j<16;j++) cnt += (key[j] <= Hk) ? 1 : 0;
  int inc = cnt;
  #pragma unroll
  for(int d=1; d<64; d<<=1){
    int t = __shfl_up(inc, d);
    if(lane >= d) inc += t;
  }
  const int m = __shfl(inc, 63);
  const int base = inc - cnt;
  int* op = idx + ((size_t)n*1024 + p)*16;
  if(m <= 64){
    unsigned long long* sc = scand[wv];
    int slot = base;
    #pragma unroll
    for(int j=0;j<16;j++){
      if(key[j] <= Hk){
        sc[slot] = ((unsigned long long)__float_as_uint(key[j]) << 10) | (unsigned)(lane + j*64);
        slot++;
      }
    }
    unsigned long long v = (lane < m) ? sc[lane] : ~0ULL;
    #pragma unroll
    for(int k=2;k<=64;k<<=1){
      #pragma unroll
      for(int j=32;j>0;j>>=1){
        if(j < k){
          unsigned long long o = __shfl_xor(v, j);
          const bool keepMax = (((lane & j)!=0) ^ ((lane & k)!=0));
          v = keepMax ? (v > o ? v : o) : (v < o ? v : o);
        }
      }
    }
    if(lane < 16) op[lane] = (int)(v & 1023u);
  } else {
    unsigned long long e[16];
    #pragma unroll
    for(int j=0;j<16;j++)
      e[j] = ((unsigned long long)__float_as_uint(key[j]) << 10) | (unsigned)(lane + j*64);
    for(int it=0; it<16; ++it){
      unsigned long long bd = e[0];
      #pragma unroll
      for(int j=1;j<16;j++) bd = (e[j] < bd) ? e[j] : bd;
      unsigned long long pk = bd;
      #pragma unroll
      for(int s=1;s<64;s<<=1){
        unsigned long long o = __shfl_xor(pk, s);
        pk = (o < pk) ? o : pk;
      }
      #pragma unroll
      for(int j=0;j<16;j++) e[j] = (e[j]==pk) ? ~0ULL : e[j];
      if(lane==0) op[it] = (int)(pk & 1023u);
    }
  }
}

// ------------------------- W prep -------------------------
__global__ void wprep_kernel(const float* __restrict__ W0, const float* __restrict__ Wsc,
                             const float* __restrict__ W1, const float* __restrict__ W2,
                             uint16_t* __restrict__ Wpp, uint16_t* __restrict__ W1p,
                             uint16_t* __restrict__ W2p){
  const int stride = gridDim.x*blockDim.x;
  const int t0 = blockIdx.x*blockDim.x + threadIdx.x;
  for(int o=t0; o<32768; o+=stride){
    int j=o&7, l=(o>>3)&63, kc=(o>>9)&1, ct=(o>>10)&3, w=o>>12;
    int k = kc*32 + (l>>4)*8 + j;
    int c = w*64 + ct*16 + (l&15);
    float val;
    if(c<128)      val = W0[k*128+c] - W0[(k+64)*128+c];
    else if(c<256) val = W0[(k+64)*128 + (c-128)];
    else           val = Wsc[k*256 + (c-256)];
    Wpp[o] = (uint16_t)f2bf(val);
  }
  for(int o=t0; o<16384; o+=stride){
    int j=o&7, l=(o>>3)&63, kc=(o>>9)&3, ct=(o>>11)&1, w=o>>12;
    int k = kc*32 + (l>>4)*8 + j, c = w*32 + ct*16 + (l&15);
    W1p[o] = (uint16_t)f2bf(W1[k*128+c]);
  }
  for(int o=t0; o<32768; o+=stride){
    int j=o&7, l=(o>>3)&63, kc=(o>>9)&3, ct=(o>>11)&3, w=o>>13;
    int k = kc*32 + (l>>4)*8 + j, c = w*64 + ct*16 + (l&15);
    W2p[o] = (uint16_t)f2bf(W2[k*256+c]);
  }
}

// ------------------------- projections (MFMA) -------------------------
__global__ __launch_bounds__(512) void proj_kernel(const float* __restrict__ feat,
    const uint16_t* __restrict__ Wpp,
    float* __restrict__ F1, float* __restrict__ F2, float* __restrict__ Fsc,
    float* __restrict__ screps){
  __shared__ alignas(16) uint16_t sA[64*64];
  const int b = blockIdx.x;
  const int tid = threadIdx.x;
  {
    const int row = tid>>3, cc = tid&7;
    const float* src = feat + ((size_t)b*64+row)*64 + cc*8;
    const float4 f0 = *(const float4*)(src);
    const float4 f1 = *(const float4*)(src+4);
    uint32_t pk[4] = { f2bf(f0.x)|(f2bf(f0.y)<<16), f2bf(f0.z)|(f2bf(f0.w)<<16),
                       f2bf(f1.x)|(f2bf(f1.y)<<16), f2bf(f1.z)|(f2bf(f1.w)<<16) };
    int bo = row*128 + cc*16; bo ^= (row&7)<<4;
    *(uint4*)((char*)sA + bo) = make_uint4(pk[0],pk[1],pk[2],pk[3]);
  }
  __syncthreads();
  const int w = tid>>6, l = tid&63;
  FragU bfr[4][2];
  #pragma unroll
  for(int ct=0;ct<4;ct++)
    #pragma unroll
    for(int kc=0;kc<2;kc++)
      bfr[ct][kc].q = *(const uint4*)(Wpp + ((size_t)((w*4+ct)*2+kc))*512 + l*8);
  f32x4 acc[4][4] = {};
  #pragma unroll
  for(int rt=0;rt<4;rt++){
    FragU a[2];
    #pragma unroll
    for(int kc=0;kc<2;kc++){
      const int row = rt*16 + (l&15);
      int bo = row*128 + kc*64 + (l>>4)*16; bo ^= (row&7)<<4;
      a[kc].q = *(const uint4*)((const char*)sA + bo);
    }
    #pragma unroll
    for(int ct=0;ct<4;ct++)
      #pragma unroll
      for(int kc=0;kc<2;kc++)
        acc[rt][ct] = __builtin_amdgcn_mfma_f32_16x16x32_bf16(a[kc].v, bfr[ct][kc].v, acc[rt][ct], 0,0,0);
  }
  #pragma unroll
  for(int rt=0;rt<4;rt++){
    #pragma unroll
    for(int ct=0;ct<4;ct++){
      const int c = w*64 + ct*16 + (l&15);
      const int rowg = b*64 + rt*16 + (l>>4)*4;
      #pragma unroll
      for(int reg=0;reg<4;reg++){
        float v = acc[rt][ct][reg];
        if(c < 128)      F1[(size_t)(rowg+reg)*128 + c] = v;
        else if(c < 256) F2[(size_t)(rowg+reg)*128 + (c-128)] = v;
        else             Fsc[(size_t)(rowg+reg)*256 + (c-256)] = v;
      }
    }
  }
  if(w>=4){
    #pragma unroll
    for(int ct=0;ct<4;ct++){
      float s=0.f, sq=0.f;
      #pragma unroll
      for(int rt=0;rt<4;rt++)
        #pragma unroll
        for(int reg=0;reg<4;reg++){ float v=acc[rt][ct][reg]; s+=v; sq+=v*v; }
      s += __shfl_xor(s,16); sq += __shfl_xor(sq,16);
      s += __shfl_xor(s,32); sq += __shfl_xor(sq,32);
      if(l<16){
        const int c = (w-4)*64 + ct*16 + l;
        atomicAdd(&screps[((b&31)*2+0)*256 + c], s);
        atomicAdd(&screps[((b&31)*2+1)*256 + c], sq);
      }
    }
  }
}

// ------------------------- y0 stats -------------------------
__global__ __launch_bounds__(256) void y0stats_kernel(const float* __restrict__ F1,
    const float* __restrict__ F2, const int* __restrict__ idx, float* __restrict__ reps){
  __shared__ int sIdx[256];
  const int tid = threadIdx.x;
  const int r0 = blockIdx.x*256;
  sIdx[tid] = idx[r0 + tid];
  __syncthreads();
  const int cg = tid & 31;
  const int rs = tid >> 5;
  const int nbase = (r0 >> 14) << 10;
  f32x4 s = {0,0,0,0}, sq = {0,0,0,0};
  for(int rr=0; rr<32; rr+=4){
    #pragma unroll
    for(int u=0;u<4;u++){
      const int r = rs*32 + rr + u;
      const int np = (r0 + r) >> 4;
      const int g = sIdx[r];
      const float4 a = *(const float4*)(F1 + (size_t)np*128 + cg*4);
      const float4 c = *(const float4*)(F2 + (size_t)(nbase + g)*128 + cg*4);
      float v0=a.x+c.x, v1=a.y+c.y, v2=a.z+c.z, v3=a.w+c.w;
      s[0]+=v0; s[1]+=v1; s[2]+=v2; s[3]+=v3;
      sq[0]+=v0*v0; sq[1]+=v1*v1; sq[2]+=v2*v2; sq[3]+=v3*v3;
    }
  }
  #pragma unroll
  for(int e=0;e<4;e++){
    s[e]  += __shfl_xor(s[e], 32);
    sq[e] += __shfl_xor(sq[e], 32);
  }
  if((tid&63) < 32){
    const int rep = blockIdx.x & 31;
    #pragma unroll
    for(int e=0;e<4;e++){
      atomicAdd(&reps[(rep*2+0)*128 + cg*4+e], s[e]);
      atomicAdd(&reps[(rep*2+1)*128 + cg*4+e], sq[e]);
    }
  }
}

// ------------------------- finalize BN -------------------------
__global__ void finalize_kernel(const float* __restrict__ reps, const float* __restrict__ gamma,
    const float* __restrict__ beta, float* __restrict__ s, float* __restrict__ t,
    int C, float inv_cnt){
  int c = threadIdx.x;
  if(c>=C) return;
  float sum=0.f, sq=0.f;
  for(int r2=0;r2<32;r2++){ sum += reps[(r2*2+0)*C + c]; sq += reps[(r2*2+1)*C + c]; }
  float m = sum*inv_cnt;
  float var = sq*inv_cnt - m*m;
  float sc = gamma[c]*rsqrtf(var + 1e-3f);
  s[c]=sc; t[c]=beta[c] - m*sc;
}

// merged: block 0 -> shortcut BN (screps), block 1 -> layer2 BN (reps2); both C=256
__global__ void finalize2x_kernel(
    const float* __restrict__ repsA, const float* __restrict__ gA, const float* __restrict__ bA,
    float* __restrict__ sA_, float* __restrict__ tA_, float invA,
    const float* __restrict__ repsB, const float* __restrict__ gB, const float* __restrict__ bB,
    float* __restrict__ sB_, float* __restrict__ tB_, float invB){
  const bool second = (blockIdx.x != 0);
  const float* reps = second ? repsB : repsA;
  const float* g    = second ? gB : gA;
  const float* bb   = second ? bB : bA;
  float* s          = second ? sB_ : sA_;
  float* t          = second ? tB_ : tA_;
  const float inv   = second ? invB : invA;
  int c = threadIdx.x;
  float sum=0.f, sq=0.f;
  for(int r2=0;r2<32;r2++){ sum += reps[(r2*2+0)*256 + c]; sq += reps[(r2*2+1)*256 + c]; }
  float m = sum*inv;
  float var = sq*inv - m*m;
  float sc = g[c]*rsqrtf(var + 1e-3f);
  s[c]=sc; t[c]=bb[c] - m*sc;
}

// ------------------------- layer1 (R15 one-shot) -------------------------
__global__ __launch_bounds__(256) void layer1_kernel(
    const float* __restrict__ F1, const float* __restrict__ F2, const int* __restrict__ idx,
    const uint16_t* __restrict__ W1p, const float* __restrict__ s0, const float* __restrict__ t0,
    uint16_t* __restrict__ y1, float* __restrict__ reps1){
  __shared__ alignas(16) uint16_t sA[64*128];
  __shared__ int sIdx[64];
  const int b = blockIdx.x;
  const int tid = threadIdx.x;
  if(tid < 64) sIdx[tid] = idx[b*64 + tid];
  const int row0 = tid>>4, q = tid&15;
  const float4 sc0a = *(const float4*)(s0 + q*8);
  const float4 sc0b = *(const float4*)(s0 + q*8 + 4);
  const float4 tt0a = *(const float4*)(t0 + q*8);
  const float4 tt0b = *(const float4*)(t0 + q*8 + 4);
  const int wv = tid>>6, l = tid&63;
  FragU bfr[2][4];
  #pragma unroll
  for(int ct=0;ct<2;ct++)
    #pragma unroll
    for(int kc=0;kc<4;kc++)
      bfr[ct][kc].q = *(const uint4*)(W1p + ((size_t)((wv*2+ct)*4+kc))*512 + l*8);
  __syncthreads();
  {
    const int npb = b*4;
    const int nbase = (b >> 8) << 10;
    int gg[4];
    #pragma unroll
    for(int jj=0;jj<4;jj++) gg[jj] = sIdx[row0 + jj*16];
    float4 va[4][4];
    #pragma unroll
    for(int jj=0;jj<4;jj++){
      const int np = npb + jj;
      const float* pf1 = F1 + (size_t)np*128 + q*8;
      const float* pf2 = F2 + (size_t)(nbase + gg[jj])*128 + q*8;
      va[jj][0] = *(const float4*)(pf1);
      va[jj][1] = *(const float4*)(pf1+4);
      va[jj][2] = *(const float4*)(pf2);
      va[jj][3] = *(const float4*)(pf2+4);
    }
    #pragma unroll
    for(int jj=0;jj<4;jj++){
      const int rw = row0 + jj*16;
      float v[8] = {va[jj][0].x+va[jj][2].x, va[jj][0].y+va[jj][2].y,
                    va[jj][0].z+va[jj][2].z, va[jj][0].w+va[jj][2].w,
                    va[jj][1].x+va[jj][3].x, va[jj][1].y+va[jj][3].y,
                    va[jj][1].z+va[jj][3].z, va[jj][1].w+va[jj][3].w};
      const float sc[8] = {sc0a.x,sc0a.y,sc0a.z,sc0a.w, sc0b.x,sc0b.y,sc0b.z,sc0b.w};
      const float tt[8] = {tt0a.x,tt0a.y,tt0a.z,tt0a.w, tt0b.x,tt0b.y,tt0b.z,tt0b.w};
      uint32_t pk[4];
      #pragma unroll
      for(int e=0;e<4;e++){
        float x0 = lrelu(sc[e*2]*v[e*2] + tt[e*2]);
        float x1 = lrelu(sc[e*2+1]*v[e*2+1] + tt[e*2+1]);
        pk[e] = f2bf(x0) | (f2bf(x1)<<16);
      }
      int bo = rw*256 + q*16; bo ^= (rw&7)<<4;
      *(uint4*)((char*)sA + bo) = make_uint4(pk[0],pk[1],pk[2],pk[3]);
    }
  }
  __syncthreads();
  f32x4 acc[4][2] = {};
  #pragma unroll
  for(int rt=0;rt<4;rt++){
    FragU a[4];
    #pragma unroll
    for(int kc=0;kc<4;kc++){
      const int rw = rt*16 + (l&15);
      int bo = rw*256 + kc*64 + (l>>4)*16; bo ^= (rw&7)<<4;
      a[kc].q = *(const uint4*)((const char*)sA + bo);
    }
    #pragma unroll
    for(int ct=0;ct<2;ct++)
      #pragma unroll
      for(int kc=0;kc<4;kc++)
        acc[rt][ct] = __builtin_amdgcn_mfma_f32_16x16x32_bf16(a[kc].v, bfr[ct][kc].v, acc[rt][ct], 0,0,0);
  }
  float ss[2]={0.f,0.f}, sq[2]={0.f,0.f};
  #pragma unroll
  for(int rt=0;rt<4;rt++)
    #pragma unroll
    for(int ct=0;ct<2;ct++)
      #pragma unroll
      for(int reg=0;reg<4;reg++){
        float v = acc[rt][ct][reg];
        ss[ct]+=v; sq[ct]+=v*v;
        const int CI = ((rt*4+wv)*2+ct)*4+reg;
        y1[(size_t)b*8192 + CI*64 + l] = (uint16_t)f2bf(v);
      }
  #pragma unroll
  for(int ct=0;ct<2;ct++){
    float a=ss[ct], b2=sq[ct];
    a += __shfl_xor(a,16); b2 += __shfl_xor(b2,16);
    a += __shfl_xor(a,32); b2 += __shfl_xor(b2,32);
    if((l>>4)==0){
      const int c = wv*32 + ct*16 + l;
      atomicAdd(&reps1[((b&31)*2+0)*128 + c], a);
      atomicAdd(&reps1[((b&31)*2+1)*128 + c], b2);
    }
  }
}

// ------------------------- layer2 pass A: stats + export transformed tiles -------------------------
__global__ __launch_bounds__(512, 4) void layer2s_kernel(
    uint16_t* __restrict__ y1, const uint16_t* __restrict__ W2p,
    const float* __restrict__ s1, const float* __restrict__ t1,
    float* __restrict__ reps2){
  __shared__ alignas(16) uint16_t sA[2][8192];
  __shared__ float sBN[256];
  const int tid = threadIdx.x;
  const int w = tid>>6, l = tid&63;
  if(tid<128){ sBN[tid]=s1[tid]; sBN[128+tid]=t1[tid]; }
  FragU bfr[2][4];
  #pragma unroll
  for(int ct=0;ct<2;ct++)
    #pragma unroll
    for(int kc=0;kc<4;kc++)
      bfr[ct][kc].q = *(const uint4*)(W2p + ((size_t)((w*2+ct)*4+kc))*512 + l*8);
  int uc0[2], ubo[2];
  #pragma unroll
  for(int k=0;k<2;k++){
    const int u = tid + k*512;
    const int l8 = u&7, CI = u>>3;
    const int reg = CI&3, ct = (CI>>2)&1, w8 = (CI>>3)&3, rt = CI>>5;
    const int row = rt*16 + (l8>>1)*4 + reg;
    const int c0 = w8*32 + ct*16 + (l8&1)*8;
    uc0[k] = c0;
    ubo[k] = (row*256 + c0*2) ^ ((row&7)<<4);
  }
  const int bt0 = blockIdx.x*16;
  uint4 va[2];
  #pragma unroll
  for(int k=0;k<2;k++)
    va[k] = *(const uint4*)(y1 + (size_t)bt0*8192 + (size_t)(tid+k*512)*8);
  __syncthreads();   // sBN ready
  #pragma unroll
  for(int k=0;k<2;k++){
    const float4 sa = *(const float4*)(&sBN[uc0[k]]);
    const float4 sb = *(const float4*)(&sBN[uc0[k]+4]);
    const float4 ta = *(const float4*)(&sBN[128+uc0[k]]);
    const float4 tb = *(const float4*)(&sBN[128+uc0[k]+4]);
    const float scv[8]={sa.x,sa.y,sa.z,sa.w, sb.x,sb.y,sb.z,sb.w};
    const float ttv[8]={ta.x,ta.y,ta.z,ta.w, tb.x,tb.y,tb.z,tb.w};
    const uint32_t e[4] = {va[k].x, va[k].y, va[k].z, va[k].w};
    uint32_t pk[4];
    #pragma unroll
    for(int j=0;j<4;j++){
      float x0 = lrelu(scv[j*2]*bf2f(e[j]&0xffffu) + ttv[j*2]);
      float x1 = lrelu(scv[j*2+1]*bf2f(e[j]>>16) + ttv[j*2+1]);
      pk[j] = f2bf(x0) | (f2bf(x1)<<16);
    }
    *(uint4*)((char*)sA[0] + ubo[k]) = make_uint4(pk[0],pk[1],pk[2],pk[3]);
  }
  __syncthreads();
  float ssA[2]={0,0}, sqA[2]={0,0};
  for(int t=0; t<16; ++t){
    const int bt = bt0 + t;
    const int p = t&1;
    if(t<15){
      #pragma unroll
      for(int k=0;k<2;k++)
        va[k] = *(const uint4*)(y1 + (size_t)(bt+1)*8192 + (size_t)(tid+k*512)*8);
    }
    f32x4 acc[4][2] = {};
    #pragma unroll
    for(int rt=0;rt<4;rt++){
      FragU a[4];
      #pragma unroll
      for(int kc=0;kc<4;kc++){
        const int rw = rt*16 + (l&15);
        int bo = rw*256 + kc*64 + (l>>4)*16; bo ^= (rw&7)<<4;
        a[kc].q = *(const uint4*)((const char*)sA[p] + bo);
      }
      if(w==0){
        #pragma unroll
        for(int kc=0;kc<4;kc++)
          *(uint4*)(y1 + (size_t)bt*8192 + (size_t)((rt*4+kc)*64 + l)*8) = a[kc].q;
      }
      #pragma unroll
      for(int ct=0;ct<2;ct++)
        #pragma unroll
        for(int kc=0;kc<4;kc++)
          acc[rt][ct] = __builtin_amdgcn_mfma_f32_16x16x32_bf16(a[kc].v, bfr[ct][kc].v, acc[rt][ct], 0,0,0);
    }
    #pragma unroll
    for(int ct=0;ct<2;ct++)
      #pragma unroll
      for(int rt=0;rt<4;rt++)
        #pragma unroll
        for(int reg=0;reg<4;reg++){
          float v = acc[rt][ct][reg];
          ssA[ct]+=v; sqA[ct]+=v*v;
        }
    if(t<15){
      #pragma unroll
      for(int k=0;k<2;k++){
        const float4 sa = *(const float4*)(&sBN[uc0[k]]);
        const float4 sb = *(const float4*)(&sBN[uc0[k]+4]);
        const float4 ta = *(const float4*)(&sBN[128+uc0[k]]);
        const float4 tb = *(const float4*)(&sBN[128+uc0[k]+4]);
        const float scv[8]={sa.x,sa.y,sa.z,sa.w, sb.x,sb.y,sb.z,sb.w};
        const float ttv[8]={ta.x,ta.y,ta.z,ta.w, tb.x,tb.y,tb.z,tb.w};
        const uint32_t e[4] = {va[k].x, va[k].y, va[k].z, va[k].w};
        uint32_t pk[4];
        #pragma unroll
        for(int j=0;j<4;j++){
          float x0 = lrelu(scv[j*2]*bf2f(e[j]&0xffffu) + ttv[j*2]);
          float x1 = lrelu(scv[j*2+1]*bf2f(e[j]>>16) + ttv[j*2+1]);
          pk[j] = f2bf(x0) | (f2bf(x1)<<16);
        }
        *(uint4*)((char*)sA[p^1] + ubo[k]) = make_uint4(pk[0],pk[1],pk[2],pk[3]);
      }
    }
    __syncthreads();
  }
  #pragma unroll
  for(int ct=0;ct<2;ct++){
    float a=ssA[ct], b2=sqA[ct];
    a += __shfl_xor(a,16); b2 += __shfl_xor(b2,16);
    a += __shfl_xor(a,32); b2 += __shfl_xor(b2,32);
    if((l>>4)==0){
      const int c = w*32 + ct*16 + l;
      const int rep = blockIdx.x & 31;
      atomicAdd(&reps2[(rep*2+0)*256 + c], a);
      atomicAdd(&reps2[(rep*2+1)*256 + c], b2);
    }
  }
}

// ------------------------- layer2 pass B: gload_lds consumer, 2 tiles/phase -------------------------
__global__ __launch_bounds__(512, 4) void layer2f_kernel(
    const uint16_t* __restrict__ y1b, const uint16_t* __restrict__ W2p,
    const float* __restrict__ s2, const float* __restrict__ t2,
    const float* __restrict__ Fsc, const float* __restrict__ ssc, const float* __restrict__ tsc,
    float* __restrict__ out){
  __shared__ alignas(16) uint16_t sA[2][16384];
  const int tid = threadIdx.x;
  const int w = tid>>6, l = tid&63;
  FragU bfr[2][4];
  #pragma unroll
  for(int ct=0;ct<2;ct++)
    #pragma unroll
    for(int kc=0;kc<4;kc++)
      bfr[ct][kc].q = *(const uint4*)(W2p + ((size_t)((w*2+ct)*4+kc))*512 + l*8);
  float sc2v[2], tt2v[2], sscv[2], tscv[2];
  #pragma unroll
  for(int ct=0;ct<2;ct++){
    const int c = w*32 + ct*16 + (l&15);
    sc2v[ct]=s2[c]; tt2v[ct]=t2[c]; sscv[ct]=ssc[c]; tscv[ct]=tsc[c];
  }
  const int bt0 = blockIdx.x*16;
  {
    const uint16_t* gp = y1b + (size_t)bt0*8192 + w*512 + l*8;
    __builtin_amdgcn_global_load_lds((const uint32_t*)gp,         (uint32_t*)&sA[0][w*512 + l*8],         16, 0, 0);
    __builtin_amdgcn_global_load_lds((const uint32_t*)(gp+4096),  (uint32_t*)&sA[0][4096 + w*512 + l*8],  16, 0, 0);
    __builtin_amdgcn_global_load_lds((const uint32_t*)(gp+8192),  (uint32_t*)&sA[0][8192 + w*512 + l*8],  16, 0, 0);
    __builtin_amdgcn_global_load_lds((const uint32_t*)(gp+12288), (uint32_t*)&sA[0][12288 + w*512 + l*8], 16, 0, 0);
  }
  __syncthreads();
  for(int ph=0; ph<8; ++ph){
    const int p = ph&1;
    if(ph<7){
      const uint16_t* gp = y1b + (size_t)(bt0 + (ph+1)*2)*8192 + w*512 + l*8;
      __builtin_amdgcn_global_load_lds((const uint32_t*)gp,         (uint32_t*)&sA[p^1][w*512 + l*8],         16, 0, 0);
      __builtin_amdgcn_global_load_lds((const uint32_t*)(gp+4096),  (uint32_t*)&sA[p^1][4096 + w*512 + l*8],  16, 0, 0);
      __builtin_amdgcn_global_load_lds((const uint32_t*)(gp+8192),  (uint32_t*)&sA[p^1][8192 + w*512 + l*8],  16, 0, 0);
      __builtin_amdgcn_global_load_lds((const uint32_t*)(gp+12288), (uint32_t*)&sA[p^1][12288 + w*512 + l*8], 16, 0, 0);
    }
    #pragma unroll
    for(int tt=0; tt<2; ++tt){
      const int bt = bt0 + ph*2 + tt;
      f32x4 acc[4][2] = {};
      #pragma unroll
      for(int rt=0;rt<4;rt++){
        FragU a[4];
        #pragma unroll
        for(int kc=0;kc<4;kc++)
          a[kc].q = *(const uint4*)((const char*)sA[p] + (size_t)tt*16384 + (size_t)((rt*4+kc)*64 + l)*16);
        #pragma unroll
        for(int ct=0;ct<2;ct++)
          #pragma unroll
          for(int kc=0;kc<4;kc++)
            acc[rt][ct] = __builtin_amdgcn_mfma_f32_16x16x32_bf16(a[kc].v, bfr[ct][kc].v, acc[rt][ct], 0,0,0);
      }
      #pragma unroll
      for(int rt=0;rt<4;rt++){
        const int np = bt*4 + rt;
        #pragma unroll
        for(int ct=0;ct<2;ct++){
          const int c = w*32 + ct*16 + (l&15);
          float s=0.f;
          #pragma unroll
          for(int reg=0;reg<4;reg++) s += lrelu(sc2v[ct]*acc[rt][ct][reg] + tt2v[ct]);
          s += __shfl_xor(s,16);
          s += __shfl_xor(s,32);
          if((l>>4)==0){
            float fts = s*(1.0f/16.0f);
            float sc = sscv[ct]*Fsc[(size_t)np*256+c] + tscv[ct];
            out[(size_t)np*256+c] = lrelu(sc + fts);
          }
        }
      }
    }
    __syncthreads();
  }
}

extern "C" void kernel_launch(void* const* d_in, const int* in_sizes, int n_in,
                              void* d_out, int out_size, void* d_ws, size_t ws_size,
                              hipStream_t stream) {
  const float* points   = (const float*)d_in[0];
  const float* features = (const float*)d_in[1];
  const float* W0  = (const float*)d_in[2];
  const float* g0  = (const float*)d_in[3];
  const float* b0  = (const float*)d_in[4];
  const float* W1  = (const float*)d_in[5];
  const float* g1  = (const float*)d_in[6];
  const float* b1  = (const float*)d_in[7];
  const float* W2  = (const float*)d_in[8];
  const float* g2  = (const float*)d_in[9];
  const float* b2  = (const float*)d_in[10];
  const float* Wsc = (const float*)d_in[11];
  const float* gsc = (const float*)d_in[12];
  const float* bsc = (const float*)d_in[13];
  float* out = (float*)d_out;

  float* ws = (float*)d_ws;
  size_t off = 0;
  float* screps = ws + off; off += 16384;    // [32][2][256]
  float* reps0  = ws + off; off += 8192;     // [32][2][128]
  float* reps1  = ws + off; off += 8192;
  float* reps2  = ws + off; off += 16384;
  float* ssc = ws + off; off += 256;
  float* tsc = ws + off; off += 256;
  float* s0  = ws + off; off += 128;
  float* t0  = ws + off; off += 128;
  float* s1v = ws + off; off += 128;
  float* t1v = ws + off; off += 128;
  float* s2v = ws + off; off += 256;
  float* t2v = ws + off; off += 256;
  int*   idxb = (int*)(ws + off); off += 524288;                 // [N*P*K]
  float* F1  = ws + off; off += (size_t)32768*128;
  float* F2  = ws + off; off += (size_t)32768*128;
  float* Fsc = ws + off; off += (size_t)32768*256;
  uint16_t* W1p = (uint16_t*)(ws + off); off += 8192;            // 16384 bf16
  uint16_t* W2p = (uint16_t*)(ws + off); off += 16384;           // 32768 bf16
  uint16_t* Wpp = (uint16_t*)(ws + off); off += 16384;           // 32768 bf16 combined proj W
  uint16_t* y1  = (uint16_t*)(ws + off); off += (size_t)33554432; // 524288*128 bf16; becomes y1b after layer2s

  // zero the stats replica region
  hipMemsetAsync(d_ws, 0, 49152*sizeof(float), stream);

  knn_kernel<<<dim3(256,32), 256, 0, stream>>>(points, idxb);
  wprep_kernel<<<128, 256, 0, stream>>>(W0, Wsc, W1, W2, Wpp, W1p, W2p);
  proj_kernel<<<512, 512, 0, stream>>>(features, Wpp, F1, F2, Fsc, screps);
  y0stats_kernel<<<2048, 256, 0, stream>>>(F1, F2, idxb, reps0);
  finalize_kernel<<<1, 128, 0, stream>>>(reps0, g0, b0, s0, t0, 128, 1.0f/524288.0f);
  layer1_kernel<<<8192, 256, 0, stream>>>(F1, F2, idxb, W1p, s0, t0, y1, reps1);
  finalize_kernel<<<1, 128, 0, stream>>>(reps1, g1, b1, s1v, t1v, 128, 1.0f/524288.0f);
  layer2s_kernel<<<512, 512, 0, stream>>>(y1, W2p, s1v, t1v, reps2);
  finalize2x_kernel<<<2, 256, 0, stream>>>(screps, gsc, bsc, ssc, tsc, 1.0f/32768.0f,
                                           reps2, g2, b2, s2v, t2v, 1.0f/524288.0f);
  layer2f_kernel<<<512, 512, 0, stream>>>(y1, W2p, s2v, t2v, Fsc, ssc, tsc, out);
}